// Round 6
// baseline (426.239 us; speedup 1.0000x reference)
//
#include <hip/hip_runtime.h>
#include <cfloat>
#include <climits>

#define NB 16
#define NC 32
#define NZ 48
#define NY 48
#define YZ 2304             // NY*NZ
#define XYZ 110592          // 48^3
#define SUM_NUM 56623104.0  // 16*32*110592
#define VPT 4               // voxels per thread (one float4, z-aligned)
#define TPB 256
#define VPB (VPT*TPB)       // 1024 voxels per block
#define PBS (XYZ/VPB)       // 108 blocks per sample
#define GRID (NB*PBS)       // 1728
#define CHK 8               // channels per chunk
#define NRND (NC/CHK)       // 4 chunk rounds

struct BP {
  float s0[NC], sx[NC], sy[NC], mx[NC];
  int   mi[NC];
  float A, B, vs, q2;
};
struct Ws { BP bp[GRID]; };

#define TOP2(m1, m2, x) do { \
    if ((x) > (m1)) { (m2) = (m1); (m1) = (x); } \
    else if ((x) > (m2)) (m2) = (x); \
  } while (0)

__global__ __launch_bounds__(256, 5) void k_fused(const float* __restrict__ f,
                                                  Ws* __restrict__ ws) {
  const int bb = blockIdx.x / PBS;
  const int pb = blockIdx.x - bb * PBS;
  const int t  = threadIdx.x;
  const int g  = pb * VPB + t * VPT;          // voxel base within sample
  const float* __restrict__ p = f + (size_t)bb * NC * XYZ + g;

  __shared__ float sb[TPB][CHK+1];            // 9.2 KB (pad 9: conflict-free)
  __shared__ float sm[TPB][CHK+1];            // 9.2 KB
  __shared__ unsigned sj[TPB];                // 1 KB
  __shared__ float sxr[TPB], syr[TPB];        // 2 KB writer (x,y) tables
  __shared__ float pc3[32][CHK][3];           // 3 KB
  __shared__ float pcv[32][CHK];              // 1 KB
  __shared__ int   pct[32][CHK];              // 1 KB
  __shared__ float rr[4][4];

  const float xf = (float)(g / YZ);
  const float yf = (float)((g / NZ) % NY);    // 4 voxels share (x,y)
  const float r2 = xf * xf + yf * yf;
  sxr[t] = xf; syr[t] = yf;                   // visible after round-0 sync #1

  // persistent per-thread state (small by design)
  float m1x=-FLT_MAX, m1y=-FLT_MAX, m1z=-FLT_MAX, m1w=-FLT_MAX;
  float m2x=-FLT_MAX, m2y=-FLT_MAX, m2z=-FLT_MAX, m2w=-FLT_MAX;
  float qsx=0.f, qsy=0.f, qsz=0.f, qsw=0.f;
  float vsum=0.f, q2acc=0.f;

  float4 v[8];
#pragma unroll
  for (int k = 0; k < CHK; ++k)
    v[k] = *reinterpret_cast<const float4*>(p + (size_t)k * XYZ);

  BP* bp = &ws->bp[blockIdx.x];

  for (int r = 0; r < NRND; ++r) {
    // ---- stats for chunk r: consume v[], stream results into LDS rows ----
    unsigned jpack = 0u;
    float chunkS0 = 0.f;
#pragma unroll
    for (int k = 0; k < CHK; ++k) {
      const float4 vv = v[k];
      const float qx = vv.x*vv.x, qy = vv.y*vv.y, qz = vv.z*vv.z, qw = vv.w*vv.w;
      qsx += qx; qsy += qy; qsz += qz; qsw += qw;
      vsum += (vv.x + vv.y) + (vv.z + vv.w);
      const float s = (qx + qy) + (qz + qw);
      chunkS0 += s;
      float m = vv.x; int j = 0;              // strict '>' keeps first index
      if (vv.y > m) { m = vv.y; j = 1; }
      if (vv.z > m) { m = vv.z; j = 2; }
      if (vv.w > m) { m = vv.w; j = 3; }
      jpack |= (unsigned)j << (2 * k);
      sb[t][k] = s; sm[t][k] = m;
      TOP2(m1x, m2x, vv.x);
      TOP2(m1y, m2y, vv.y);
      TOP2(m1z, m2z, vv.z);
      TOP2(m1w, m2w, vv.w);
    }
    sj[t] = jpack;
    q2acc = fmaf(chunkS0, r2, q2acc);

    // ---- issue next chunk's loads; they fly across the whole epilogue ----
    if (r + 1 < NRND) {
      const float* pn = p + (size_t)(CHK * (r + 1)) * XYZ;
#pragma unroll
      for (int k = 0; k < CHK; ++k)
        v[k] = *reinterpret_cast<const float4*>(pn + (size_t)k * XYZ);
    }
    __syncthreads();                          // sync #1: rows ready

    // ---- level 1: 32 groups x 8 channels; each scans 8 rows ----
    {
      const int cc = t & 7, ch = t >> 3;
      float a0 = 0.f, a1 = 0.f, a2 = 0.f, bm = -FLT_MAX; int bt = 0;
#pragma unroll
      for (int j = 0; j < 8; ++j) {
        const int row = ch * 8 + j;           // ascending row = ascending voxel
        const float s = sb[row][cc];
        a0 += s;
        a1 = fmaf(s, sxr[row], a1);
        a2 = fmaf(s, syr[row], a2);
        const float vm = sm[row][cc];
        if (vm > bm) { bm = vm; bt = row; }
      }
      pc3[ch][cc][0] = a0; pc3[ch][cc][1] = a1; pc3[ch][cc][2] = a2;
      pcv[ch][cc] = bm; pct[ch][cc] = bt;
    }
    __syncthreads();                          // sync #2: partials ready

    // ---- level 2: 8 threads, one channel each ----
    if (t < CHK) {
      float b0 = 0.f, b1 = 0.f, b2 = 0.f, bm = -FLT_MAX; int brow = 0;
      for (int pp = 0; pp < 32; ++pp) {       // ascending keeps first on ties
        b0 += pc3[pp][t][0]; b1 += pc3[pp][t][1]; b2 += pc3[pp][t][2];
        const float vm = pcv[pp][t];
        if (vm > bm) { bm = vm; brow = pct[pp][t]; }
      }
      const int c = CHK * r + t;
      const int j = (int)((sj[brow] >> (2 * t)) & 3u);
      bp->s0[c] = b0; bp->sx[c] = b1; bp->sy[c] = b2;
      bp->mx[c] = bm; bp->mi[c] = pb * VPB + brow * VPT + j;
    }
    __syncthreads();                          // sync #3: LDS reusable
  }

  // ---- per-voxel div moments from the global top-2 ----
  float A = 0.f, Bv = 0.f;
  {
    float q, rst;
    q = m1x*m1x; rst = qsx - q; A += q*rst + m2x*m2x*q; Bv += m1x*rst + m2x*q;
    q = m1y*m1y; rst = qsy - q; A += q*rst + m2y*m2y*q; Bv += m1y*rst + m2y*q;
    q = m1z*m1z; rst = qsz - q; A += q*rst + m2z*m2z*q; Bv += m1z*rst + m2z*q;
    q = m1w*m1w; rst = qsw - q; A += q*rst + m2w*m2w*q; Bv += m1w*rst + m2w*q;
  }

  for (int off = 32; off > 0; off >>= 1) {
    A     += __shfl_down(A,     off);
    Bv    += __shfl_down(Bv,    off);
    vsum  += __shfl_down(vsum,  off);
    q2acc += __shfl_down(q2acc, off);
  }
  const int w = t >> 6, l = t & 63;
  if (l == 0) { rr[w][0] = A; rr[w][1] = Bv; rr[w][2] = vsum; rr[w][3] = q2acc; }
  __syncthreads();
  if (t == 0) {
    bp->A  = (rr[0][0]+rr[1][0]) + (rr[2][0]+rr[3][0]);
    bp->B  = (rr[0][1]+rr[1][1]) + (rr[2][1]+rr[3][1]);
    bp->vs = (rr[0][2]+rr[1][2]) + (rr[2][2]+rr[3][2]);
    bp->q2 = (rr[0][3]+rr[1][3]) + (rr[2][3]+rr[3][3]);
  }
}

// ---- finalize: thread = (b,c); merge 108 block partials; assemble in f64 ----
__global__ __launch_bounds__(512) void k_fin(const Ws* __restrict__ ws,
                                             float* __restrict__ out) {
  const int t = threadIdx.x;
  const int b = t >> 5, c = t & 31;
  double s0 = 0, sx = 0, sy = 0;
  float mv = -FLT_MAX; int mi = INT_MAX;
  for (int k = 0; k < PBS; ++k) {
    const BP* p = &ws->bp[b * PBS + k];
    s0 += p->s0[c]; sx += p->sx[c]; sy += p->sy[c];
    const float ov = p->mx[c]; const int oi = p->mi[c];
    if (ov > mv || (ov == mv && oi < mi)) { mv = ov; mi = oi; }
  }
  const double mx = (double)(mi / YZ);
  const double my = (double)((mi / NZ) % NY);
  const double mz = (double)(mi % NZ);
  // per-(b,c) part of dis: cross terms + analytic dz^2 (x^2+y^2 moment is global)
  double dis = (mx*mx + my*my) * s0 - 2.0*mx*sx - 2.0*my*sy
             + 2304.0 * (48.0*mz*mz - 2256.0*mz + 35720.0);
  double s0t = s0, a = 0.0, bb2 = 0.0, vsm = 0.0, q2 = 0.0;
  for (int i = t; i < GRID; i += 512) {
    a += ws->bp[i].A; bb2 += ws->bp[i].B; vsm += ws->bp[i].vs; q2 += ws->bp[i].q2;
  }

  for (int off = 32; off > 0; off >>= 1) {
    dis += __shfl_down(dis, off);
    s0t += __shfl_down(s0t, off);
    a   += __shfl_down(a,   off);
    bb2 += __shfl_down(bb2, off);
    vsm += __shfl_down(vsm, off);
    q2  += __shfl_down(q2,  off);
  }
  __shared__ double sd[8][6];
  const int wid = t >> 6;
  if ((t & 63) == 0) {
    sd[wid][0]=dis; sd[wid][1]=s0t; sd[wid][2]=a;
    sd[wid][3]=bb2; sd[wid][4]=vsm; sd[wid][5]=q2;
  }
  __syncthreads();
  if (t == 0) {
    for (int q = 1; q < 8; ++q) {
      dis += sd[q][0]; s0t += sd[q][1]; a += sd[q][2];
      bb2 += sd[q][3]; vsm += sd[q][4]; q2 += sd[q][5];
    }
    const double mgr = vsm / SUM_NUM;
    out[0] = (float)((dis + q2) / SUM_NUM);
    out[1] = (float)((a - 2.0*mgr*bb2 + mgr*mgr*s0t) / SUM_NUM);
  }
}

extern "C" void kernel_launch(void* const* d_in, const int* in_sizes, int n_in,
                              void* d_out, int out_size, void* d_ws, size_t ws_size,
                              hipStream_t stream) {
  const float* f = (const float*)d_in[0];
  Ws* ws = (Ws*)d_ws;
  float* out = (float*)d_out;
  hipLaunchKernelGGL(k_fused, dim3(GRID), dim3(TPB), 0, stream, f, ws);
  hipLaunchKernelGGL(k_fin,   dim3(1),    dim3(512), 0, stream, ws, out);
}

// Round 7
// 337.892 us; speedup vs baseline: 1.2615x; 1.2615x over previous
//
#include <hip/hip_runtime.h>
#include <cfloat>
#include <climits>

#define NB 16
#define NC 32
#define NZ 48
#define NY 48
#define YZ 2304             // NY*NZ
#define XYZ 110592          // 48^3
#define SUM_NUM 56623104.0  // 16*32*110592
#define VPT 4               // voxels per thread (one float4, z-aligned)
#define TPB 256
#define VPB (VPT*TPB)       // 1024 voxels per block
#define PBS (XYZ/VPB)       // 108 blocks per sample
#define GRID (NB*PBS)       // 1728
#define CHK 8               // channels per chunk
#define NRND (NC/CHK)       // 4 chunk rounds

struct BP {
  float s0[NC], sx[NC], sy[NC], mx[NC];
  int   mi[NC];
  float A, B, vs, q2;
};
struct Ws { BP bp[GRID]; };

#define TOP2(m1, m2, x) do { \
    if ((x) > (m1)) { (m2) = (m1); (m1) = (x); } \
    else if ((x) > (m2)) (m2) = (x); \
  } while (0)

// NOTE: 2nd arg = MIN waves per EU -> VGPR cap = 512/arg. (256,5) forced a
// 48-reg allocation and 472 MB of scratch spill (round-6 counters). (256,4)
// caps at 128 regs: fits the ~100-reg natural demand, still 16 waves/CU.
__global__ __launch_bounds__(256, 4) void k_fused(const float* __restrict__ f,
                                                  Ws* __restrict__ ws) {
  const int bb = blockIdx.x / PBS;
  const int pb = blockIdx.x - bb * PBS;
  const int t  = threadIdx.x;
  const int g  = pb * VPB + t * VPT;          // voxel base within sample
  const float* __restrict__ p = f + (size_t)bb * NC * XYZ + g;

  __shared__ float sb[TPB][CHK+1];            // 9.2 KB (pad 9: conflict-free)
  __shared__ float sm[TPB][CHK+1];            // 9.2 KB
  __shared__ unsigned sj[TPB];                // 1 KB
  __shared__ float sxr[TPB], syr[TPB];        // 2 KB writer (x,y) tables
  __shared__ float pc3[32][CHK][3];           // 3 KB
  __shared__ float pcv[32][CHK];              // 1 KB
  __shared__ int   pct[32][CHK];              // 1 KB
  __shared__ float rr[4][4];

  const float xf = (float)(g / YZ);
  const float yf = (float)((g / NZ) % NY);    // 4 voxels share (x,y)
  const float r2 = xf * xf + yf * yf;
  sxr[t] = xf; syr[t] = yf;                   // visible after round-0 sync #1

  // persistent per-thread state (small by design)
  float m1x=-FLT_MAX, m1y=-FLT_MAX, m1z=-FLT_MAX, m1w=-FLT_MAX;
  float m2x=-FLT_MAX, m2y=-FLT_MAX, m2z=-FLT_MAX, m2w=-FLT_MAX;
  float qsx=0.f, qsy=0.f, qsz=0.f, qsw=0.f;
  float vsum=0.f, q2acc=0.f;

  float4 v[CHK];
#pragma unroll
  for (int k = 0; k < CHK; ++k)
    v[k] = *reinterpret_cast<const float4*>(p + (size_t)k * XYZ);

  BP* bp = &ws->bp[blockIdx.x];

  for (int r = 0; r < NRND; ++r) {
    // ---- stats for chunk r: consume v[], stream results into LDS rows ----
    unsigned jpack = 0u;
    float chunkS0 = 0.f;
#pragma unroll
    for (int k = 0; k < CHK; ++k) {
      const float4 vv = v[k];
      const float qx = vv.x*vv.x, qy = vv.y*vv.y, qz = vv.z*vv.z, qw = vv.w*vv.w;
      qsx += qx; qsy += qy; qsz += qz; qsw += qw;
      vsum += (vv.x + vv.y) + (vv.z + vv.w);
      const float s = (qx + qy) + (qz + qw);
      chunkS0 += s;
      float m = vv.x; int j = 0;              // strict '>' keeps first index
      if (vv.y > m) { m = vv.y; j = 1; }
      if (vv.z > m) { m = vv.z; j = 2; }
      if (vv.w > m) { m = vv.w; j = 3; }
      jpack |= (unsigned)j << (2 * k);
      sb[t][k] = s; sm[t][k] = m;
      TOP2(m1x, m2x, vv.x);
      TOP2(m1y, m2y, vv.y);
      TOP2(m1z, m2z, vv.z);
      TOP2(m1w, m2w, vv.w);
    }
    sj[t] = jpack;
    q2acc = fmaf(chunkS0, r2, q2acc);

    // ---- issue next chunk's loads; they fly across the whole epilogue ----
    if (r + 1 < NRND) {
      const float* pn = p + (size_t)(CHK * (r + 1)) * XYZ;
#pragma unroll
      for (int k = 0; k < CHK; ++k)
        v[k] = *reinterpret_cast<const float4*>(pn + (size_t)k * XYZ);
    }
    __syncthreads();                          // sync #1: rows ready

    // ---- level 1: 32 groups x 8 channels; each scans 8 rows ----
    {
      const int cc = t & 7, ch = t >> 3;
      float a0 = 0.f, a1 = 0.f, a2 = 0.f, bm = -FLT_MAX; int bt = 0;
#pragma unroll
      for (int j = 0; j < 8; ++j) {
        const int row = ch * 8 + j;           // ascending row = ascending voxel
        const float s = sb[row][cc];
        a0 += s;
        a1 = fmaf(s, sxr[row], a1);
        a2 = fmaf(s, syr[row], a2);
        const float vm = sm[row][cc];
        if (vm > bm) { bm = vm; bt = row; }
      }
      pc3[ch][cc][0] = a0; pc3[ch][cc][1] = a1; pc3[ch][cc][2] = a2;
      pcv[ch][cc] = bm; pct[ch][cc] = bt;
    }
    __syncthreads();                          // sync #2: partials ready

    // ---- level 2: 8 threads, one channel each ----
    if (t < CHK) {
      float b0 = 0.f, b1 = 0.f, b2 = 0.f, bm = -FLT_MAX; int brow = 0;
      for (int pp = 0; pp < 32; ++pp) {       // ascending keeps first on ties
        b0 += pc3[pp][t][0]; b1 += pc3[pp][t][1]; b2 += pc3[pp][t][2];
        const float vm = pcv[pp][t];
        if (vm > bm) { bm = vm; brow = pct[pp][t]; }
      }
      const int c = CHK * r + t;
      const int j = (int)((sj[brow] >> (2 * t)) & 3u);
      bp->s0[c] = b0; bp->sx[c] = b1; bp->sy[c] = b2;
      bp->mx[c] = bm; bp->mi[c] = pb * VPB + brow * VPT + j;
    }
    __syncthreads();                          // sync #3: LDS reusable
  }

  // ---- per-voxel div moments from the global top-2 ----
  float A = 0.f, Bv = 0.f;
  {
    float q, rst;
    q = m1x*m1x; rst = qsx - q; A += q*rst + m2x*m2x*q; Bv += m1x*rst + m2x*q;
    q = m1y*m1y; rst = qsy - q; A += q*rst + m2y*m2y*q; Bv += m1y*rst + m2y*q;
    q = m1z*m1z; rst = qsz - q; A += q*rst + m2z*m2z*q; Bv += m1z*rst + m2z*q;
    q = m1w*m1w; rst = qsw - q; A += q*rst + m2w*m2w*q; Bv += m1w*rst + m2w*q;
  }

  for (int off = 32; off > 0; off >>= 1) {
    A     += __shfl_down(A,     off);
    Bv    += __shfl_down(Bv,    off);
    vsum  += __shfl_down(vsum,  off);
    q2acc += __shfl_down(q2acc, off);
  }
  const int w = t >> 6, l = t & 63;
  if (l == 0) { rr[w][0] = A; rr[w][1] = Bv; rr[w][2] = vsum; rr[w][3] = q2acc; }
  __syncthreads();
  if (t == 0) {
    bp->A  = (rr[0][0]+rr[1][0]) + (rr[2][0]+rr[3][0]);
    bp->B  = (rr[0][1]+rr[1][1]) + (rr[2][1]+rr[3][1]);
    bp->vs = (rr[0][2]+rr[1][2]) + (rr[2][2]+rr[3][2]);
    bp->q2 = (rr[0][3]+rr[1][3]) + (rr[2][3]+rr[3][3]);
  }
}

// ---- finalize: thread = (b,c); merge 108 block partials; assemble in f64 ----
__global__ __launch_bounds__(512) void k_fin(const Ws* __restrict__ ws,
                                             float* __restrict__ out) {
  const int t = threadIdx.x;
  const int b = t >> 5, c = t & 31;
  double s0 = 0, sx = 0, sy = 0;
  float mv = -FLT_MAX; int mi = INT_MAX;
  for (int k = 0; k < PBS; ++k) {
    const BP* p = &ws->bp[b * PBS + k];
    s0 += p->s0[c]; sx += p->sx[c]; sy += p->sy[c];
    const float ov = p->mx[c]; const int oi = p->mi[c];
    if (ov > mv || (ov == mv && oi < mi)) { mv = ov; mi = oi; }
  }
  const double mx = (double)(mi / YZ);
  const double my = (double)((mi / NZ) % NY);
  const double mz = (double)(mi % NZ);
  // per-(b,c) part of dis: cross terms + analytic dz^2 (x^2+y^2 moment is global)
  double dis = (mx*mx + my*my) * s0 - 2.0*mx*sx - 2.0*my*sy
             + 2304.0 * (48.0*mz*mz - 2256.0*mz + 35720.0);
  double s0t = s0, a = 0.0, bb2 = 0.0, vsm = 0.0, q2 = 0.0;
  for (int i = t; i < GRID; i += 512) {
    a += ws->bp[i].A; bb2 += ws->bp[i].B; vsm += ws->bp[i].vs; q2 += ws->bp[i].q2;
  }

  for (int off = 32; off > 0; off >>= 1) {
    dis += __shfl_down(dis, off);
    s0t += __shfl_down(s0t, off);
    a   += __shfl_down(a,   off);
    bb2 += __shfl_down(bb2, off);
    vsm += __shfl_down(vsm, off);
    q2  += __shfl_down(q2,  off);
  }
  __shared__ double sd[8][6];
  const int wid = t >> 6;
  if ((t & 63) == 0) {
    sd[wid][0]=dis; sd[wid][1]=s0t; sd[wid][2]=a;
    sd[wid][3]=bb2; sd[wid][4]=vsm; sd[wid][5]=q2;
  }
  __syncthreads();
  if (t == 0) {
    for (int q = 1; q < 8; ++q) {
      dis += sd[q][0]; s0t += sd[q][1]; a += sd[q][2];
      bb2 += sd[q][3]; vsm += sd[q][4]; q2 += sd[q][5];
    }
    const double mgr = vsm / SUM_NUM;
    out[0] = (float)((dis + q2) / SUM_NUM);
    out[1] = (float)((a - 2.0*mgr*bb2 + mgr*mgr*s0t) / SUM_NUM);
  }
}

extern "C" void kernel_launch(void* const* d_in, const int* in_sizes, int n_in,
                              void* d_out, int out_size, void* d_ws, size_t ws_size,
                              hipStream_t stream) {
  const float* f = (const float*)d_in[0];
  Ws* ws = (Ws*)d_ws;
  float* out = (float*)d_out;
  hipLaunchKernelGGL(k_fused, dim3(GRID), dim3(TPB), 0, stream, f, ws);
  hipLaunchKernelGGL(k_fin,   dim3(1),    dim3(512), 0, stream, ws, out);
}

// Round 8
// 133.487 us; speedup vs baseline: 3.1931x; 2.5313x over previous
//
#include <hip/hip_runtime.h>
#include <cfloat>
#include <climits>

#define NB 16
#define NC 32
#define NZ 48
#define NY 48
#define YZ 2304             // NY*NZ
#define XYZ 110592          // 48^3
#define SUM_NUM 56623104.0  // 16*32*110592
#define TPB 256
#define BPS 48              // blocks per sample = NX; block pb owns x == pb
#define GRID (NB*BPS)       // 768 = exactly 3 blocks/CU
#define NRND 3              // rounds; each covers 768 voxels (3 stripes of 256)

struct SP {
  float s0[NC], sy[NC], mx[NC];
  int   mi[NC];
  float q2, vs, A, B;
};
struct Ws { SP sp[GRID]; };

#define TOP2(m1, m2, x) do { \
    if ((x) > (m1)) { (m2) = (m1); (m1) = (x); } \
    else if ((x) > (m2)) (m2) = (x); \
  } while (0)

__global__ __launch_bounds__(256) void k_fused(const float* __restrict__ f,
                                               Ws* __restrict__ ws) {
  const int bb = blockIdx.x / BPS;
  const int pb = blockIdx.x - bb * BPS;      // x index of this block's slab
  const int t  = threadIdx.x;
  const int w  = t >> 6, l = t & 63;
  const float* __restrict__ gbase = f + (size_t)bb * NC * XYZ + pb * YZ;

  // wave w owns channels 8w..8w+7; x block-constant, y f4-constant =>
  // per-channel state is only {s0, sy, max, idx}. Nothing else persists.
  float s0K[8], syK[8], mvK[8];
  int   miK[8];
#pragma unroll
  for (int k = 0; k < 8; ++k) {
    s0K[k] = 0.f; syK[k] = 0.f; mvK[k] = -FLT_MAX; miK[k] = 0;
  }
  float q2a = 0.f, vsa = 0.f, A = 0.f, Bv = 0.f;
  const float x2 = (float)(pb * pb);

  const float* __restrict__ wbase = gbase + (size_t)(8 * w) * XYZ;

  for (int r = 0; r < NRND; ++r) {
    // ---- A-phase: stripes j=3r..3r+2; this wave's 8 channels ----
#pragma unroll
    for (int jj = 0; jj < 3; ++jj) {
      const int s  = 4 * l + 256 * (3 * r + jj);   // slab voxel (s = y*48+z)
      const float yf = (float)(s / NZ);            // same y for all 4 elems
      const float w2 = x2 + yf * yf;
      const float* ps = wbase + s;
#pragma unroll
      for (int k = 0; k < 8; ++k) {
        const float4 v = *reinterpret_cast<const float4*>(ps + (size_t)k * XYZ);
        const float qx = v.x*v.x, qy = v.y*v.y, qz = v.z*v.z, qw = v.w*v.w;
        const float sf = (qx + qy) + (qz + qw);
        s0K[k] += sf;
        syK[k]  = fmaf(yf, sf, syK[k]);
        q2a     = fmaf(w2, sf, q2a);
        vsa    += (v.x + v.y) + (v.z + v.w);
        float m = v.x; int e = 0;                  // strict '>': first index
        if (v.y > m) { m = v.y; e = 1; }
        if (v.z > m) { m = v.z; e = 2; }
        if (v.w > m) { m = v.w; e = 3; }
        if (m > mvK[k]) { mvK[k] = m; miK[k] = s + e; }
      }
    }
    __syncthreads();   // drains A loads -> lines resident in L2/L3 for B

    // ---- B-phase: same 768 voxels, all 32 channels, from cache ----
    if (t < 192) {                                 // 192 f4-slots per round
      const float* pB = gbase + 4 * (192 * r + t);
      float m1x=-FLT_MAX, m1y=-FLT_MAX, m1z=-FLT_MAX, m1w=-FLT_MAX;
      float m2x=-FLT_MAX, m2y=-FLT_MAX, m2z=-FLT_MAX, m2w=-FLT_MAX;
      float qsx=0.f, qsy=0.f, qsz=0.f, qsw=0.f;
#pragma unroll 8
      for (int c = 0; c < NC; ++c) {
        const float4 v = *reinterpret_cast<const float4*>(pB + (size_t)c * XYZ);
        qsx = fmaf(v.x, v.x, qsx);
        qsy = fmaf(v.y, v.y, qsy);
        qsz = fmaf(v.z, v.z, qsz);
        qsw = fmaf(v.w, v.w, qsw);
        TOP2(m1x, m2x, v.x);
        TOP2(m1y, m2y, v.y);
        TOP2(m1z, m2z, v.z);
        TOP2(m1w, m2w, v.w);
      }
      float q, rst;
      q = m1x*m1x; rst = qsx - q; A += q*rst + m2x*m2x*q; Bv += m1x*rst + m2x*q;
      q = m1y*m1y; rst = qsy - q; A += q*rst + m2y*m2y*q; Bv += m1y*rst + m2y*q;
      q = m1z*m1z; rst = qsz - q; A += q*rst + m2z*m2z*q; Bv += m1z*rst + m2z*q;
      q = m1w*m1w; rst = qsw - q; A += q*rst + m2w*m2w*q; Bv += m1w*rst + m2w*q;
    }
    // no barrier needed here: next A-phase touches no shared state
  }

  // ---- epilogue: wave-reduce owned channels; block-reduce scalars ----
  SP* sp = &ws->sp[blockIdx.x];
#pragma unroll
  for (int k = 0; k < 8; ++k) {
    float s0 = s0K[k], sy = syK[k], mv = mvK[k];
    int mi = miK[k];
    for (int off = 32; off > 0; off >>= 1) {
      s0 += __shfl_down(s0, off);
      sy += __shfl_down(sy, off);
      const float ov = __shfl_down(mv, off);
      const int   oi = __shfl_down(mi, off);
      if (ov > mv || (ov == mv && oi < mi)) { mv = ov; mi = oi; }
    }
    if (l == 0) {
      const int c = 8 * w + k;
      sp->s0[c] = s0; sp->sy[c] = sy; sp->mx[c] = mv;
      sp->mi[c] = pb * YZ + mi;                    // sample-local voxel index
    }
  }

  __shared__ float rr[4][4];
  for (int off = 32; off > 0; off >>= 1) {
    q2a += __shfl_down(q2a, off);
    vsa += __shfl_down(vsa, off);
    A   += __shfl_down(A,   off);
    Bv  += __shfl_down(Bv,  off);
  }
  if (l == 0) { rr[w][0] = q2a; rr[w][1] = vsa; rr[w][2] = A; rr[w][3] = Bv; }
  __syncthreads();
  if (t == 0) {
    sp->q2 = (rr[0][0]+rr[1][0]) + (rr[2][0]+rr[3][0]);
    sp->vs = (rr[0][1]+rr[1][1]) + (rr[2][1]+rr[3][1]);
    sp->A  = (rr[0][2]+rr[1][2]) + (rr[2][2]+rr[3][2]);
    sp->B  = (rr[0][3]+rr[1][3]) + (rr[2][3]+rr[3][3]);
  }
}

// ---- finalize: thread = (b,c); merge 48 slab partials; assemble in f64 ----
__global__ __launch_bounds__(512) void k_fin(const Ws* __restrict__ ws,
                                             float* __restrict__ out) {
  const int t = threadIdx.x;
  const int b = t >> 5, c = t & 31;
  double s0 = 0, sx = 0, sy = 0;
  float mv = -FLT_MAX; int mi = INT_MAX;
  for (int k = 0; k < BPS; ++k) {                  // ascending x keeps first
    const SP* p = &ws->sp[b * BPS + k];
    const double s = p->s0[c];
    s0 += s; sx += (double)k * s; sy += p->sy[c];  // x == k for slab k
    const float ov = p->mx[c]; const int oi = p->mi[c];
    if (ov > mv || (ov == mv && oi < mi)) { mv = ov; mi = oi; }
  }
  const double mx = (double)(mi / YZ);
  const double my = (double)((mi / NZ) % NY);
  const double mz = (double)(mi % NZ);
  // per-(b,c) dis part (q2 = global sum of sq*(x^2+y^2) added once below)
  double dis = (mx*mx + my*my) * s0 - 2.0*mx*sx - 2.0*my*sy
             + 2304.0 * (48.0*mz*mz - 2256.0*mz + 35720.0);
  double s0t = s0, a = 0.0, bb2 = 0.0, vsm = 0.0, q2 = 0.0;
  for (int i = t; i < GRID; i += 512) {
    q2 += ws->sp[i].q2; vsm += ws->sp[i].vs;
    a  += ws->sp[i].A;  bb2 += ws->sp[i].B;
  }

  for (int off = 32; off > 0; off >>= 1) {
    dis += __shfl_down(dis, off);
    s0t += __shfl_down(s0t, off);
    a   += __shfl_down(a,   off);
    bb2 += __shfl_down(bb2, off);
    vsm += __shfl_down(vsm, off);
    q2  += __shfl_down(q2,  off);
  }
  __shared__ double sd[8][6];
  const int wid = t >> 6;
  if ((t & 63) == 0) {
    sd[wid][0]=dis; sd[wid][1]=s0t; sd[wid][2]=a;
    sd[wid][3]=bb2; sd[wid][4]=vsm; sd[wid][5]=q2;
  }
  __syncthreads();
  if (t == 0) {
    for (int q = 1; q < 8; ++q) {
      dis += sd[q][0]; s0t += sd[q][1]; a += sd[q][2];
      bb2 += sd[q][3]; vsm += sd[q][4]; q2 += sd[q][5];
    }
    const double mgr = vsm / SUM_NUM;
    out[0] = (float)((dis + q2) / SUM_NUM);
    out[1] = (float)((a - 2.0*mgr*bb2 + mgr*mgr*s0t) / SUM_NUM);
  }
}

extern "C" void kernel_launch(void* const* d_in, const int* in_sizes, int n_in,
                              void* d_out, int out_size, void* d_ws, size_t ws_size,
                              hipStream_t stream) {
  const float* f = (const float*)d_in[0];
  Ws* ws = (Ws*)d_ws;
  float* out = (float*)d_out;
  hipLaunchKernelGGL(k_fused, dim3(GRID), dim3(TPB), 0, stream, f, ws);
  hipLaunchKernelGGL(k_fin,   dim3(1),    dim3(512), 0, stream, ws, out);
}

// Round 9
// 74.662 us; speedup vs baseline: 5.7089x; 1.7879x over previous
//
#include <hip/hip_runtime.h>
#include <cfloat>
#include <climits>

#define NB 16
#define NC 32
#define NBC (NB*NC)         // 512
#define NZ 48
#define NY 48
#define YZ 2304             // NY*NZ
#define XYZ 110592          // 48^3
#define Q (XYZ/4)           // 27648 float4 per (b,c)
#define SUM_NUM 56623104.0  // 16*32*110592
#define NBLK_B 108          // B-role blocks per sample (108*256*4 voxels)
#define K2_BLOCKS (NB*NBLK_B)
#define RPS 140             // roles per sample: 32 A + 108 B
#define GRID (NB*RPS)       // 2240

struct Ws {
  int   amax[NBC];
  float vsum[NBC], S0[NBC], Sx[NBC], Sy[NBC], Sq2[NBC];
  float pA[K2_BLOCKS], pB[K2_BLOCKS];
};

#define TOP2(m1, m2, x) do { \
    if ((x) > (m1)) { (m2) = (m1); (m1) = (x); } \
    else if ((x) > (m2)) (m2) = (x); \
  } while (0)

// One dispatch, two block roles, interleaved per sample so role-A's HBM
// fetches are L2/L3-hits for role-B (and vice versa). Proportional
// interleave: role A iff floor(32(r+1)/140) > floor(32r/140).
__global__ __launch_bounds__(256) void k_all(const float* __restrict__ f,
                                             Ws* __restrict__ ws) {
  const int b = blockIdx.x / RPS;
  const int r = blockIdx.x - b * RPS;
  const int t = threadIdx.x;
  const int w = t >> 6, l = t & 63;
  const int fA  = (32 * r) / RPS;
  const int fA1 = (32 * (r + 1)) / RPS;

  if (fA1 > fA) {
    // ================= role A: per-(b,c) moments + argmax =================
    const int bc = b * NC + fA;
    const float4* __restrict__ p = reinterpret_cast<const float4*>(f + (size_t)bc * XYZ);
    float bmax = -FLT_MAX; int bidx = 0;
    float vs = 0.f, s0 = 0.f, sx = 0.f, sy = 0.f, sq2 = 0.f;
#pragma unroll 4
    for (int i = t; i < Q; i += 256) {
      const float4 v = p[i];
      const int base = i << 2;
      const float xf = (float)(i / 576);          // 576 f4 per x-slab
      const float yf = (float)((i / 12) % 48);    // 12 f4 per y-row
      const float sq = (v.x*v.x + v.y*v.y) + (v.z*v.z + v.w*v.w);
      vs += (v.x + v.y) + (v.z + v.w);
      s0 += sq;
      sx  = fmaf(sq, xf, sx);
      sy  = fmaf(sq, yf, sy);
      sq2 = fmaf(sq, fmaf(xf, xf, yf*yf), sq2);
      float m = v.x; int e = 0;                   // strict '>': first index
      if (v.y > m) { m = v.y; e = 1; }
      if (v.z > m) { m = v.z; e = 2; }
      if (v.w > m) { m = v.w; e = 3; }
      if (m > bmax) { bmax = m; bidx = base + e; }
    }
    for (int off = 32; off > 0; off >>= 1) {
      vs  += __shfl_down(vs,  off);
      s0  += __shfl_down(s0,  off);
      sx  += __shfl_down(sx,  off);
      sy  += __shfl_down(sy,  off);
      sq2 += __shfl_down(sq2, off);
      const float ov = __shfl_down(bmax, off);
      const int   oi = __shfl_down(bidx, off);
      if (ov > bmax || (ov == bmax && oi < bidx)) { bmax = ov; bidx = oi; }
    }
    __shared__ float svs[4], ss0[4], ssx[4], ssy[4], ssq2[4], smx[4];
    __shared__ int   sbi[4];
    if (l == 0) { svs[w]=vs; ss0[w]=s0; ssx[w]=sx; ssy[w]=sy; ssq2[w]=sq2;
                  smx[w]=bmax; sbi[w]=bidx; }
    __syncthreads();
    if (t == 0) {
      for (int q = 1; q < 4; ++q) {
        vs += svs[q]; s0 += ss0[q]; sx += ssx[q]; sy += ssy[q]; sq2 += ssq2[q];
        if (smx[q] > bmax || (smx[q] == bmax && sbi[q] < bidx)) { bmax = smx[q]; bidx = sbi[q]; }
      }
      ws->amax[bc] = bidx; ws->vsum[bc] = vs; ws->S0[bc] = s0;
      ws->Sx[bc] = sx; ws->Sy[bc] = sy; ws->Sq2[bc] = sq2;
    }
  } else {
    // ================= role B: per-voxel channel top-2 ====================
    const int sblk = r - fA1;                     // 0..107
    const float4* __restrict__ p =
        reinterpret_cast<const float4*>(f + (size_t)b * NC * XYZ) + (sblk * 256 + t);
    float m1x=-FLT_MAX, m1y=-FLT_MAX, m1z=-FLT_MAX, m1w=-FLT_MAX;
    float m2x=-FLT_MAX, m2y=-FLT_MAX, m2z=-FLT_MAX, m2w=-FLT_MAX;
    float4 s0 = make_float4(0.f, 0.f, 0.f, 0.f);
#pragma unroll 8
    for (int c = 0; c < NC; ++c) {
      const float4 v = p[(size_t)c * Q];
      s0.x = fmaf(v.x, v.x, s0.x);
      s0.y = fmaf(v.y, v.y, s0.y);
      s0.z = fmaf(v.z, v.z, s0.z);
      s0.w = fmaf(v.w, v.w, s0.w);
      TOP2(m1x, m2x, v.x);
      TOP2(m1y, m2y, v.y);
      TOP2(m1z, m2z, v.z);
      TOP2(m1w, m2w, v.w);
    }
    float A = 0.f, Bv = 0.f;
    {
      float q1, rest;
      q1 = m1x*m1x; rest = s0.x - q1;
      A = fmaf(q1, rest, A); A = fmaf(m2x*m2x, q1, A);
      Bv = fmaf(m1x, rest, Bv); Bv = fmaf(m2x, q1, Bv);
      q1 = m1y*m1y; rest = s0.y - q1;
      A = fmaf(q1, rest, A); A = fmaf(m2y*m2y, q1, A);
      Bv = fmaf(m1y, rest, Bv); Bv = fmaf(m2y, q1, Bv);
      q1 = m1z*m1z; rest = s0.z - q1;
      A = fmaf(q1, rest, A); A = fmaf(m2z*m2z, q1, A);
      Bv = fmaf(m1z, rest, Bv); Bv = fmaf(m2z, q1, Bv);
      q1 = m1w*m1w; rest = s0.w - q1;
      A = fmaf(q1, rest, A); A = fmaf(m2w*m2w, q1, A);
      Bv = fmaf(m1w, rest, Bv); Bv = fmaf(m2w, q1, Bv);
    }
    for (int off = 32; off > 0; off >>= 1) {
      A  += __shfl_down(A,  off);
      Bv += __shfl_down(Bv, off);
    }
    __shared__ float rA[4], rB[4];
    if (l == 0) { rA[w] = A; rB[w] = Bv; }
    __syncthreads();
    if (t == 0) {
      const int pidx = b * NBLK_B + sblk;
      ws->pA[pidx] = (rA[0] + rA[1]) + (rA[2] + rA[3]);
      ws->pB[pidx] = (rB[0] + rB[1]) + (rB[2] + rB[3]);
    }
  }
}

// ---------------- Finalize (verified in round 2): assemble in f64 ----------
__global__ __launch_bounds__(512) void k_fin(const Ws* __restrict__ ws,
                                             float* __restrict__ out) {
  const int t = threadIdx.x;
  double dis, vs, c0, a = 0.0, bb = 0.0;
  {
    const int idx = ws->amax[t];
    const double mx = (double)(idx / YZ);
    const double my = (double)((idx / NZ) % NY);
    const double mz = (double)(idx % NZ);
    const double S0 = ws->S0[t], Sx = ws->Sx[t], Sy = ws->Sy[t], Sq2 = ws->Sq2[t];
    dis = Sq2 - 2.0*mx*Sx - 2.0*my*Sy + (mx*mx + my*my)*S0
        + 2304.0 * (48.0*mz*mz - 2256.0*mz + 35720.0);
    vs = ws->vsum[t];
    c0 = S0;
  }
  for (int i = t; i < K2_BLOCKS; i += 512) { a += ws->pA[i]; bb += ws->pB[i]; }

  for (int off = 32; off > 0; off >>= 1) {
    dis += __shfl_down(dis, off);
    vs  += __shfl_down(vs,  off);
    c0  += __shfl_down(c0,  off);
    a   += __shfl_down(a,   off);
    bb  += __shfl_down(bb,  off);
  }
  __shared__ double sd[8][5];
  const int wid = t >> 6;
  if ((t & 63) == 0) { sd[wid][0]=dis; sd[wid][1]=vs; sd[wid][2]=c0; sd[wid][3]=a; sd[wid][4]=bb; }
  __syncthreads();
  if (t == 0) {
    for (int q = 1; q < 8; ++q) {
      dis += sd[q][0]; vs += sd[q][1]; c0 += sd[q][2]; a += sd[q][3]; bb += sd[q][4];
    }
    const double mgr = vs / SUM_NUM;
    out[0] = (float)(dis / SUM_NUM);
    out[1] = (float)((a - 2.0*mgr*bb + mgr*mgr*c0) / SUM_NUM);
  }
}

extern "C" void kernel_launch(void* const* d_in, const int* in_sizes, int n_in,
                              void* d_out, int out_size, void* d_ws, size_t ws_size,
                              hipStream_t stream) {
  const float* f = (const float*)d_in[0];
  Ws* ws = (Ws*)d_ws;
  float* out = (float*)d_out;
  hipLaunchKernelGGL(k_all, dim3(GRID), dim3(256), 0, stream, f, ws);
  hipLaunchKernelGGL(k_fin, dim3(1),    dim3(512), 0, stream, ws, out);
}